// Round 4
// baseline (1460.812 us; speedup 1.0000x reference)
//
#include <hip/hip_runtime.h>
#include <math.h>
#include <stddef.h>

#define N_NODES 16384
#define F_DIM   500
#define E_DIM   128
#define C_DIM   10
#define B_DIM   4096
#define MAXDEG  128

typedef __attribute__((ext_vector_type(8))) short short8;   // 8 bf16 = 4 VGPRs
typedef __attribute__((ext_vector_type(4))) float f32x4;    // MFMA C/D

__device__ inline unsigned short f2bf(float f) {
    union { float f; unsigned int u; } v; v.f = f;
    unsigned int u = v.u;
    u += 0x7FFFu + ((u >> 16) & 1u);        // RNE
    return (unsigned short)(u >> 16);
}
__device__ inline float bf2f(unsigned short u) {
    union { unsigned int u; float f; } v; v.u = (unsigned int)u << 16;
    return v.f;
}

// ---------------------------------------------------------------------------
// K1 (block-ranged, all independent front-end work co-scheduled):
//  [0,4096):      adj scan -> CSR. WAVE-PER-ROW: 4 waves/block, no LDS,
//                 no barriers, no atomics. Ballot+popcount compaction,
//                 1-deep prefetch keeps loads in flight continuously.
//  [4096,4160):   W2ab16[n][k] = bf16(W2[n][k])
//  [4160,4224):   W2bb16[n][k] = bf16(W2[n][128+k])
//  [4224,4240):   Wl1t[k][e] = Wl1[e][k]   (fp32 transpose)
//  [4240,4752):   GEMM1, LDS-staged coalesced (fp32->bf16 during staging):
//                 Xb16[32-row tile][256] = bf16(data) @ bf16(W1)^T
// ---------------------------------------------------------------------------
__global__ __launch_bounds__(256) void k_front(const float* __restrict__ adj,
                                               const float* __restrict__ data,
                                               const float* __restrict__ W1,
                                               const float* __restrict__ W2,
                                               const float* __restrict__ Wl1,
                                               unsigned short* __restrict__ nbr,
                                               int* __restrict__ deg,
                                               unsigned short* __restrict__ Xb16,
                                               unsigned short* __restrict__ W2ab16,
                                               unsigned short* __restrict__ W2bb16,
                                               float* __restrict__ Wl1t) {
    const int bb = blockIdx.x;
    const int tid = threadIdx.x;

    if (bb < 4096) {
        // ---------------- wave-per-row adj scan ----------------
        const int lane = tid & 63;
        const int row = bb * 4 + (tid >> 6);
        const float4* r4 = (const float4*)(adj + (size_t)row * N_NODES);
        const size_t nb = (size_t)row * MAXDEG;
        const unsigned long long lowm = ~0ull >> (64 - lane - 1) >> 1;  // bits < lane
        int base = 0;
#define PROC1(val, cix) do {                                                  \
        bool p = (val) != 0.f;                                                \
        unsigned long long m = __ballot(p);                                   \
        if (p) {                                                              \
            int pos = base + (int)__popcll(m & lowm);                         \
            if (pos < MAXDEG) nbr[nb + pos] = (unsigned short)(cix);          \
        }                                                                     \
        base += (int)__popcll(m);                                             \
    } while (0)
#define PROC4(vv, tt) do {                                                    \
        int colb = ((tt) * 64 + lane) * 4;                                    \
        PROC1((vv).x, colb);                                                  \
        PROC1((vv).y, colb + 1);                                              \
        PROC1((vv).z, colb + 2);                                              \
        PROC1((vv).w, colb + 3);                                              \
    } while (0)
        float4 cur = r4[lane];
#pragma unroll 4
        for (int t = 0; t < 63; ++t) {
            float4 nxt = r4[(t + 1) * 64 + lane];
            PROC4(cur, t);
            cur = nxt;
        }
        PROC4(cur, 63);
#undef PROC4
#undef PROC1
        if (lane == 0) deg[row] = (base > MAXDEG) ? MAXDEG : base;  // deg>=1
        return;
    } else if (bb < 4160) {                        // W2 self-half -> bf16
        int idx = (bb - 4096) * 256 + tid;         // 128*128
        int n = idx >> 7, k = idx & 127;
        W2ab16[idx] = f2bf(W2[(size_t)n * 256 + k]);
        return;
    } else if (bb < 4224) {                        // W2 neigh-half -> bf16
        int idx = (bb - 4160) * 256 + tid;
        int n = idx >> 7, k = idx & 127;
        W2bb16[idx] = f2bf(W2[(size_t)n * 256 + 128 + k]);
        return;
    } else if (bb < 4240) {                        // Wl1 transpose (fp32)
        __shared__ float tile[32][33];
        int tb = bb - 4224;                        // 16 tiles (4x4)
        int k0 = (tb & 3) * 32, e0 = (tb >> 2) * 32;
        int tx = tid & 31, ty0 = tid >> 5;
#pragma unroll
        for (int q = 0; q < 4; ++q) {
            int ty = ty0 + q * 8;
            tile[ty][tx] = Wl1[(size_t)(e0 + ty) * 128 + k0 + tx];
        }
        __syncthreads();
#pragma unroll
        for (int q = 0; q < 4; ++q) {
            int ty = ty0 + q * 8;
            Wl1t[(size_t)(k0 + ty) * 128 + e0 + tx] = tile[tx][ty];
        }
        return;
    }
    // ---------------- GEMM1, LDS-staged coalesced ----------------
    __shared__ unsigned short sA[32 * 40];
    __shared__ unsigned short sB[256 * 40];
    const int g = bb - 4240;
    const int blockM = g * 32;
    const int w    = tid >> 6;              // wave: output cols w*64..w*64+63
    const int lane = tid & 63;
    const int l16  = lane & 15;
    const int quad = lane >> 4;
    f32x4 acc[2][4] = {};
#pragma unroll 1
    for (int c = 0; c < 16; ++c) {          // K = 512 (500 + zero pad)
        const int k0 = c << 5;
        {   // A tile: 32 rows x 32 cols fp32 -> bf16 (1 float4/thread)
            int row = tid >> 3, ch = tid & 7;
            int k = k0 + ch * 4;
            const float* p = data + (size_t)(blockM + row) * F_DIM + k;
            float4 f = (k + 4 <= F_DIM) ? *(const float4*)p
                                        : make_float4(0.f, 0.f, 0.f, 0.f);
            ushort4 u;
            u.x = f2bf(f.x); u.y = f2bf(f.y); u.z = f2bf(f.z); u.w = f2bf(f.w);
            *(ushort4*)(sA + row * 40 + ch * 4) = u;
        }
#pragma unroll
        for (int q = 0; q < 8; ++q) {       // B tile: 256 rows x 32 cols
            int idx = tid + 256 * q;
            int row = idx >> 3, ch = idx & 7;
            int k = k0 + ch * 4;
            const float* p = W1 + (size_t)(row & 127) * 1000 + (row >> 7) * F_DIM + k;
            float4 f = (k + 4 <= F_DIM) ? *(const float4*)p
                                        : make_float4(0.f, 0.f, 0.f, 0.f);
            ushort4 u;
            u.x = f2bf(f.x); u.y = f2bf(f.y); u.z = f2bf(f.z); u.w = f2bf(f.w);
            *(ushort4*)(sB + row * 40 + ch * 4) = u;
        }
        __syncthreads();
        short8 af[2], bfr[4];
#pragma unroll
        for (int mt = 0; mt < 2; ++mt)
            af[mt] = *(const short8*)(sA + (mt * 16 + l16) * 40 + quad * 8);
#pragma unroll
        for (int nt = 0; nt < 4; ++nt)
            bfr[nt] = *(const short8*)(sB + (w * 64 + nt * 16 + l16) * 40 + quad * 8);
#pragma unroll
        for (int mt = 0; mt < 2; ++mt)
#pragma unroll
            for (int nt = 0; nt < 4; ++nt)
                acc[mt][nt] = __builtin_amdgcn_mfma_f32_16x16x32_bf16(af[mt], bfr[nt], acc[mt][nt], 0, 0, 0);
        __syncthreads();
    }
    // C/D layout: col = lane&15, row = quad*4 + reg
#pragma unroll
    for (int mt = 0; mt < 2; ++mt)
#pragma unroll
        for (int nt = 0; nt < 4; ++nt) {
            int col = w * 64 + nt * 16 + l16;
#pragma unroll
            for (int r = 0; r < 4; ++r) {
                int row = blockM + mt * 16 + quad * 4 + r;
                Xb16[(size_t)row * 256 + col] = f2bf(acc[mt][nt][r]);
            }
        }
}

// ---------------------------------------------------------------------------
// K2: layer-1 gather + relu + l2norm. One block per node (8 groups x 32).
// H1b[i] = bf16( l2norm(relu(Xa[i] + mean_j Xb[j] + b1)) )
// ---------------------------------------------------------------------------
__global__ __launch_bounds__(256) void k_gather(const unsigned short* __restrict__ nbr,
                                                const int* __restrict__ deg,
                                                const unsigned short* __restrict__ Xb16,
                                                const float* __restrict__ b1,
                                                unsigned short* __restrict__ H1b) {
    const int i = blockIdx.x;
    const int t = threadIdx.x;
    const int cnt = deg[i];
    __shared__ int s_idx[MAXDEG];
    __shared__ float s_part[8][128];
    __shared__ float s_w[2];
    if (t < cnt) s_idx[t] = nbr[(size_t)i * MAXDEG + t];
    __syncthreads();
    const int g = t >> 5, l = t & 31;
    float4 a4 = make_float4(0.f, 0.f, 0.f, 0.f);
    for (int k = g; k < cnt; k += 8) {
        ushort4 x4 = ((const ushort4*)(Xb16 + (size_t)s_idx[k] * 256 + 128))[l];
        a4.x += bf2f(x4.x); a4.y += bf2f(x4.y); a4.z += bf2f(x4.z); a4.w += bf2f(x4.w);
    }
    *(float4*)&s_part[g][l * 4] = a4;
    __syncthreads();
    float vv = 0.f;
    if (t < 128) {
        float tot = 0.f;
#pragma unroll
        for (int g2 = 0; g2 < 8; ++g2) tot += s_part[g2][t];
        vv = bf2f(Xb16[(size_t)i * 256 + t]) + tot / (float)cnt + b1[t];
        vv = fmaxf(vv, 0.f);
        float s = vv * vv;
#pragma unroll
        for (int off = 32; off > 0; off >>= 1) s += __shfl_down(s, off, 64);
        if ((t & 63) == 0) s_w[t >> 6] = s;
    }
    __syncthreads();
    if (t < 128) {
        float denom = fmaxf(sqrtf(s_w[0] + s_w[1]), 1e-12f);
        H1b[(size_t)i * 128 + t] = f2bf(vv / denom);
    }
}

// ---------------------------------------------------------------------------
// K3: GEMM2 — no LDS, no barriers. B (128x128 bf16, 32KB) is L2-resident.
//  [0,512):   Yb16 = bf16(H1b @ W2b^T)   for all nodes
//  [512,640): Ya   = H1b[nodes] @ W2a^T  (fp32) for batch rows
// ---------------------------------------------------------------------------
__global__ __launch_bounds__(256) void k_gemm2(const unsigned short* __restrict__ H1b,
                                               const unsigned short* __restrict__ W2bb16,
                                               const unsigned short* __restrict__ W2ab16,
                                               const int* __restrict__ nodes,
                                               unsigned short* __restrict__ Yb16,
                                               float* __restrict__ Ya) {
    const int bb = blockIdx.x;
    const bool selfp = (bb >= 512);
    const unsigned short* B = selfp ? W2ab16 : W2bb16;
    const int blockM = (selfp ? (bb - 512) : bb) * 32;
    const int tid  = threadIdx.x;
    const int w    = tid >> 6;
    const int lane = tid & 63;
    const int l16  = lane & 15;
    const int quad = lane >> 4;
    int rsrc0 = blockM + l16,      rsrc1 = blockM + 16 + l16;
    if (selfp) { rsrc0 = nodes[rsrc0]; rsrc1 = nodes[rsrc1]; }
    short8 af[2][4], bfr[2][4];
#pragma unroll
    for (int c = 0; c < 4; ++c) {
        af[0][c] = *(const short8*)(H1b + (size_t)rsrc0 * 128 + c * 32 + quad * 8);
        af[1][c] = *(const short8*)(H1b + (size_t)rsrc1 * 128 + c * 32 + quad * 8);
    }
#pragma unroll
    for (int nt = 0; nt < 2; ++nt) {
        int n = w * 32 + nt * 16 + l16;
#pragma unroll
        for (int c = 0; c < 4; ++c)
            bfr[nt][c] = *(const short8*)(B + (size_t)n * 128 + c * 32 + quad * 8);
    }
    f32x4 acc[2][2] = {};
#pragma unroll
    for (int c = 0; c < 4; ++c)
#pragma unroll
        for (int mt = 0; mt < 2; ++mt)
#pragma unroll
            for (int nt = 0; nt < 2; ++nt)
                acc[mt][nt] = __builtin_amdgcn_mfma_f32_16x16x32_bf16(af[mt][c], bfr[nt][c], acc[mt][nt], 0, 0, 0);
#pragma unroll
    for (int mt = 0; mt < 2; ++mt)
#pragma unroll
        for (int nt = 0; nt < 2; ++nt) {
            int col = w * 32 + nt * 16 + l16;
#pragma unroll
            for (int r = 0; r < 4; ++r) {
                int row = blockM + mt * 16 + quad * 4 + r;
                if (selfp) Ya[(size_t)row * 128 + col] = acc[mt][nt][r];
                else       Yb16[(size_t)row * 128 + col] = f2bf(acc[mt][nt][r]);
            }
        }
}

// ---------------------------------------------------------------------------
// K4: layer-2 epilogue + classifier + softmax. ONE WAVE PER BATCH NODE.
// ---------------------------------------------------------------------------
__global__ __launch_bounds__(256) void k_l2head(const int* __restrict__ nodes,
                                                const unsigned short* __restrict__ nbr,
                                                const int* __restrict__ deg,
                                                const unsigned short* __restrict__ Yb16,
                                                const float* __restrict__ Ya,
                                                const float* __restrict__ b2,
                                                const float* __restrict__ Wl1t,
                                                const float* __restrict__ bl1,
                                                const float* __restrict__ Wl2,
                                                const float* __restrict__ bl2,
                                                float* __restrict__ out) {
    const int lane = threadIdx.x & 63;
    const int b = blockIdx.x * 4 + (threadIdx.x >> 6);
    const int n = nodes[b];
    const int cnt = deg[n];
    const int myn  = (lane < cnt)      ? (int)nbr[(size_t)n * MAXDEG + lane]      : 0;
    const int myn2 = (lane + 64 < cnt) ? (int)nbr[(size_t)n * MAXDEG + lane + 64] : 0;
    const int half = lane >> 5, l32 = lane & 31;
    float ax = 0.f, ay = 0.f, az = 0.f, aw = 0.f;
    for (int k = half; k < cnt; k += 2) {
        int kk = k & 63;
        int j1 = __shfl(myn, kk);
        int j2 = __shfl(myn2, kk);
        int j = (k < 64) ? j1 : j2;
        ushort4 y4 = *(const ushort4*)(Yb16 + (size_t)j * 128 + l32 * 4);
        ax += bf2f(y4.x); ay += bf2f(y4.y); az += bf2f(y4.z); aw += bf2f(y4.w);
    }
    ax += __shfl_xor(ax, 32); ay += __shfl_xor(ay, 32);
    az += __shfl_xor(az, 32); aw += __shfl_xor(aw, 32);
    float4 ya = *(const float4*)(Ya + (size_t)b * 128 + l32 * 4);
    float4 bb = *(const float4*)(b2 + l32 * 4);
    float fc = (float)cnt;
    float h0 = fmaxf(ya.x + ax / fc + bb.x, 0.f);
    float h1 = fmaxf(ya.y + ay / fc + bb.y, 0.f);
    float h2 = fmaxf(ya.z + az / fc + bb.z, 0.f);
    float h3 = fmaxf(ya.w + aw / fc + bb.w, 0.f);
    float s = h0 * h0 + h1 * h1 + h2 * h2 + h3 * h3;
#pragma unroll
    for (int off = 16; off > 0; off >>= 1) s += __shfl_xor(s, off);
    float rden = 1.0f / fmaxf(sqrtf(s), 1e-12f);
    h0 *= rden; h1 *= rden; h2 *= rden; h3 *= rden;
    // Lin: x[e] for e = 2*lane, 2*lane+1 (covers 128 cols across the wave)
    float2 bl = *(const float2*)(bl1 + 2 * lane);
    float x0 = bl.x, x1 = bl.y;
    const float* wl = Wl1t + 2 * lane;
    for (int m = 0; m < 32; ++m) {
        float k0 = __shfl(h0, m), k1 = __shfl(h1, m), k2 = __shfl(h2, m), k3 = __shfl(h3, m);
        float2 w0 = *(const float2*)(wl + (size_t)(m * 4 + 0) * 128);
        float2 w1 = *(const float2*)(wl + (size_t)(m * 4 + 1) * 128);
        float2 w2 = *(const float2*)(wl + (size_t)(m * 4 + 2) * 128);
        float2 w3 = *(const float2*)(wl + (size_t)(m * 4 + 3) * 128);
        x0 += k0 * w0.x + k1 * w1.x + k2 * w2.x + k3 * w3.x;
        x1 += k0 * w0.y + k1 * w1.y + k2 * w2.y + k3 * w3.y;
    }
    // head: 10 outputs, each a 64-lane tree reduce of 2-elem partials
    float cv[C_DIM];
#pragma unroll
    for (int cc = 0; cc < C_DIM; ++cc) {
        float2 w = *(const float2*)(Wl2 + (size_t)cc * 128 + 2 * lane);
        float p = x0 * w.x + x1 * w.y;
#pragma unroll
        for (int off = 32; off > 0; off >>= 1) p += __shfl_xor(p, off);
        cv[cc] = p + bl2[cc];
    }
    float mx = cv[0];
#pragma unroll
    for (int cc = 1; cc < C_DIM; ++cc) mx = fmaxf(mx, cv[cc]);
    float se = 0.f;
#pragma unroll
    for (int cc = 0; cc < C_DIM; ++cc) { cv[cc] = expf(cv[cc] - mx); se += cv[cc]; }
    float rse = 1.0f / se;
    float o = cv[0];
#pragma unroll
    for (int cc = 1; cc < C_DIM; ++cc) o = (lane == cc) ? cv[cc] : o;
    if (lane < C_DIM) out[(size_t)b * C_DIM + lane] = o * rse;
}

// ---------------------------------------------------------------------------
// Launch
// ---------------------------------------------------------------------------
extern "C" void kernel_launch(void* const* d_in, const int* in_sizes, int n_in,
                              void* d_out, int out_size, void* d_ws, size_t ws_size,
                              hipStream_t stream) {
    const int*   nodes = (const int*)  d_in[0];
    const float* adj   = (const float*)d_in[1];
    const float* data  = (const float*)d_in[2];
    const float* W1    = (const float*)d_in[3];
    const float* b1    = (const float*)d_in[4];
    const float* W2    = (const float*)d_in[5];
    const float* b2    = (const float*)d_in[6];
    const float* Wl1   = (const float*)d_in[7];
    const float* bl1   = (const float*)d_in[8];
    const float* Wl2   = (const float*)d_in[9];
    const float* bl2   = (const float*)d_in[10];
    float* out = (float*)d_out;

    // workspace: fp32 first, then bf16/ushort, then int (16B aligned)
    float* Wl1t = (float*)d_ws;                              // 128*128
    float* Ya   = Wl1t + 16384;                              // 4096*128
    unsigned short* W2ab16 = (unsigned short*)(Ya + (size_t)B_DIM * 128); // 128*128
    unsigned short* W2bb16 = W2ab16 + 16384;                 // 128*128
    unsigned short* Xb16   = W2bb16 + 16384;                 // 16384*256
    unsigned short* H1b    = Xb16 + (size_t)N_NODES * 256;   // 16384*128
    unsigned short* Yb16   = H1b + (size_t)N_NODES * 128;    // 16384*128
    unsigned short* nbr    = Yb16 + (size_t)N_NODES * 128;   // 16384*128
    int* deg = (int*)(nbr + (size_t)N_NODES * MAXDEG);       // 16384

    // K1: wave-per-row scan (4096) + prep (144) + LDS-coalesced GEMM1 (512)
    k_front<<<4096 + 144 + 512, 256, 0, stream>>>(adj, data, W1, W2, Wl1,
                                                  nbr, deg, Xb16,
                                                  W2ab16, W2bb16, Wl1t);
    // K2: layer-1 gather + relu + l2norm
    k_gather<<<N_NODES, 256, 0, stream>>>(nbr, deg, Xb16, b1, H1b);
    // K3: barrier-less GEMM2 (Yb all nodes + Ya batch rows)
    k_gemm2<<<512 + 128, 256, 0, stream>>>(H1b, W2bb16, W2ab16, nodes, Yb16, Ya);
    // K4: wave-per-batch-node layer-2 + head
    k_l2head<<<B_DIM / 4, 256, 0, stream>>>(nodes, nbr, deg, Yb16, Ya, b2,
                                            Wl1t, bl1, Wl2, bl2, out);
}

// Round 5
// 1455.330 us; speedup vs baseline: 1.0038x; 1.0038x over previous
//
#include <hip/hip_runtime.h>
#include <math.h>
#include <stddef.h>

#define N_NODES 16384
#define F_DIM   500
#define E_DIM   128
#define C_DIM   10
#define B_DIM   4096
#define MAXDEG  128

typedef __attribute__((ext_vector_type(8))) short short8;   // 8 bf16 = 4 VGPRs
typedef __attribute__((ext_vector_type(4))) float f32x4;    // MFMA C/D

__device__ inline unsigned short f2bf(float f) {
    union { float f; unsigned int u; } v; v.f = f;
    unsigned int u = v.u;
    u += 0x7FFFu + ((u >> 16) & 1u);        // RNE
    return (unsigned short)(u >> 16);
}
__device__ inline float bf2f(unsigned short u) {
    union { unsigned int u; float f; } v; v.u = (unsigned int)u << 16;
    return v.f;
}

// ---------------------------------------------------------------------------
// K1 (block-ranged; must complete before K2 since K2 consumes Xb16):
//  [0,64):    W2ab16[n][k] = bf16(W2[n][k])
//  [64,128):  W2bb16[n][k] = bf16(W2[n][128+k])
//  [128,144): Wl1t[k][e] = Wl1[e][k]   (fp32 transpose)
//  [144,656): GEMM1, LDS-staged coalesced (fp32->bf16 during staging):
//             Xb16[32-row tile][256] = bf16(data) @ bf16(W1)^T
// ---------------------------------------------------------------------------
__global__ __launch_bounds__(256) void k_prep1(const float* __restrict__ data,
                                               const float* __restrict__ W1,
                                               const float* __restrict__ W2,
                                               const float* __restrict__ Wl1,
                                               unsigned short* __restrict__ Xb16,
                                               unsigned short* __restrict__ W2ab16,
                                               unsigned short* __restrict__ W2bb16,
                                               float* __restrict__ Wl1t) {
    const int bb = blockIdx.x;
    const int tid = threadIdx.x;

    if (bb < 64) {                                 // W2 self-half -> bf16
        int idx = bb * 256 + tid;                  // 128*128
        int n = idx >> 7, k = idx & 127;
        W2ab16[idx] = f2bf(W2[(size_t)n * 256 + k]);
        return;
    } else if (bb < 128) {                         // W2 neigh-half -> bf16
        int idx = (bb - 64) * 256 + tid;
        int n = idx >> 7, k = idx & 127;
        W2bb16[idx] = f2bf(W2[(size_t)n * 256 + 128 + k]);
        return;
    } else if (bb < 144) {                         // Wl1 transpose (fp32)
        __shared__ float tile[32][33];
        int tb = bb - 128;                         // 16 tiles (4x4)
        int k0 = (tb & 3) * 32, e0 = (tb >> 2) * 32;
        int tx = tid & 31, ty0 = tid >> 5;
#pragma unroll
        for (int q = 0; q < 4; ++q) {
            int ty = ty0 + q * 8;
            tile[ty][tx] = Wl1[(size_t)(e0 + ty) * 128 + k0 + tx];
        }
        __syncthreads();
#pragma unroll
        for (int q = 0; q < 4; ++q) {
            int ty = ty0 + q * 8;
            Wl1t[(size_t)(k0 + ty) * 128 + e0 + tx] = tile[tx][ty];
        }
        return;
    }
    // ---------------- GEMM1, LDS-staged coalesced ----------------
    __shared__ unsigned short sA[32 * 40];
    __shared__ unsigned short sB[256 * 40];
    const int g = bb - 144;
    const int blockM = g * 32;
    const int w    = tid >> 6;              // wave: output cols w*64..w*64+63
    const int lane = tid & 63;
    const int l16  = lane & 15;
    const int quad = lane >> 4;
    f32x4 acc[2][4] = {};
#pragma unroll 1
    for (int c = 0; c < 16; ++c) {          // K = 512 (500 + zero pad)
        const int k0 = c << 5;
        {   // A tile: 32 rows x 32 cols fp32 -> bf16 (1 float4/thread)
            int row = tid >> 3, ch = tid & 7;
            int k = k0 + ch * 4;
            const float* p = data + (size_t)(blockM + row) * F_DIM + k;
            float4 f = (k + 4 <= F_DIM) ? *(const float4*)p
                                        : make_float4(0.f, 0.f, 0.f, 0.f);
            ushort4 u;
            u.x = f2bf(f.x); u.y = f2bf(f.y); u.z = f2bf(f.z); u.w = f2bf(f.w);
            *(ushort4*)(sA + row * 40 + ch * 4) = u;
        }
#pragma unroll
        for (int q = 0; q < 8; ++q) {       // B tile: 256 rows x 32 cols
            int idx = tid + 256 * q;
            int row = idx >> 3, ch = idx & 7;
            int k = k0 + ch * 4;
            const float* p = W1 + (size_t)(row & 127) * 1000 + (row >> 7) * F_DIM + k;
            float4 f = (k + 4 <= F_DIM) ? *(const float4*)p
                                        : make_float4(0.f, 0.f, 0.f, 0.f);
            ushort4 u;
            u.x = f2bf(f.x); u.y = f2bf(f.y); u.z = f2bf(f.z); u.w = f2bf(f.w);
            *(ushort4*)(sB + row * 40 + ch * 4) = u;
        }
        __syncthreads();
        short8 af[2], bfr[4];
#pragma unroll
        for (int mt = 0; mt < 2; ++mt)
            af[mt] = *(const short8*)(sA + (mt * 16 + l16) * 40 + quad * 8);
#pragma unroll
        for (int nt = 0; nt < 4; ++nt)
            bfr[nt] = *(const short8*)(sB + (w * 64 + nt * 16 + l16) * 40 + quad * 8);
#pragma unroll
        for (int mt = 0; mt < 2; ++mt)
#pragma unroll
            for (int nt = 0; nt < 4; ++nt)
                acc[mt][nt] = __builtin_amdgcn_mfma_f32_16x16x32_bf16(af[mt], bfr[nt], acc[mt][nt], 0, 0, 0);
        __syncthreads();
    }
    // C/D layout: col = lane&15, row = quad*4 + reg
#pragma unroll
    for (int mt = 0; mt < 2; ++mt)
#pragma unroll
        for (int nt = 0; nt < 4; ++nt) {
            int col = w * 64 + nt * 16 + l16;
#pragma unroll
            for (int r = 0; r < 4; ++r) {
                int row = blockM + mt * 16 + quad * 4 + r;
                Xb16[(size_t)row * 256 + col] = f2bf(acc[mt][nt][r]);
            }
        }
}

// ---------------------------------------------------------------------------
// K2: FUSED adj-scan + layer-1 aggregation + relu + l2norm. WAVE PER ROW.
// No LDS, no barriers, no atomics. Stream the 64KB adj row 2-deep prefetched;
// per nonzero (uniform scalar bit-loop over the ballot mask): one coalesced
// 256B fetch of Xb16[j] neighbor-half accumulated into 2 f32/lane, plus a
// CSR write (nbr, for layer-2 reuse). Epilogue: relu + l2norm in-wave.
// Aggregation is reference-exact (all nonzeros, divide by full rowsum).
// ---------------------------------------------------------------------------
__global__ __launch_bounds__(256) void k_scanagg(const float* __restrict__ adj,
                                                 const unsigned short* __restrict__ Xb16,
                                                 const float* __restrict__ b1,
                                                 unsigned short* __restrict__ nbr,
                                                 int* __restrict__ deg,
                                                 unsigned short* __restrict__ H1b) {
    const int lane = threadIdx.x & 63;
    const int row = blockIdx.x * 4 + (threadIdx.x >> 6);
    const float4* r4 = (const float4*)(adj + (size_t)row * N_NODES);
    const size_t nb = (size_t)row * MAXDEG;
    int base = 0;
    float a0 = 0.f, a1 = 0.f;               // cols 2*lane, 2*lane+1 (f32 acc)
    float4 cur = r4[lane];
    float4 nxt = r4[64 + lane];
#pragma unroll 2
    for (int t = 0; t < 64; ++t) {
        int pf = (t + 2 < 64) ? (t + 2) : 63;           // clamped prefetch
        float4 nn2 = r4[pf * 64 + lane];
#pragma unroll
        for (int c = 0; c < 4; ++c) {
            float val = (c == 0) ? cur.x : (c == 1) ? cur.y : (c == 2) ? cur.z : cur.w;
            unsigned long long m = __ballot(val != 0.f);
            while (m) {                      // uniform scalar loop, no divergence
                int b = (int)__builtin_ctzll(m);
                m &= m - 1;
                int j = ((t * 64 + b) << 2) + c;
                unsigned int u = ((const unsigned int*)(Xb16 + (size_t)j * 256 + 128))[lane];
                a0 += bf2f((unsigned short)(u & 0xffffu));
                a1 += bf2f((unsigned short)(u >> 16));
                if (lane == 0 && base < MAXDEG) nbr[nb + base] = (unsigned short)j;
                ++base;
            }
        }
        cur = nxt;
        nxt = nn2;
    }
    if (lane == 0) deg[row] = base;          // full rowsum (deg >= 1, self-loop)
    // ---- epilogue: self + mean + bias, relu, l2norm ----
    unsigned int su = ((const unsigned int*)(Xb16 + (size_t)row * 256))[lane];
    float2 bb = *(const float2*)(b1 + 2 * lane);
    float fc = (float)base;
    float v0 = fmaxf(bf2f((unsigned short)(su & 0xffffu)) + a0 / fc + bb.x, 0.f);
    float v1 = fmaxf(bf2f((unsigned short)(su >> 16))     + a1 / fc + bb.y, 0.f);
    float s = v0 * v0 + v1 * v1;
#pragma unroll
    for (int off = 32; off > 0; off >>= 1) s += __shfl_xor(s, off);
    float rden = 1.0f / fmaxf(sqrtf(s), 1e-12f);
    unsigned int o = (unsigned int)f2bf(v0 * rden) | ((unsigned int)f2bf(v1 * rden) << 16);
    ((unsigned int*)(H1b + (size_t)row * 128))[lane] = o;
}

// ---------------------------------------------------------------------------
// K3: GEMM2 — no LDS, no barriers. B (128x128 bf16, 32KB) is L2-resident.
//  [0,512):   Yb16 = bf16(H1b @ W2b^T)   for all nodes
//  [512,640): Ya   = H1b[nodes] @ W2a^T  (fp32) for batch rows
// ---------------------------------------------------------------------------
__global__ __launch_bounds__(256) void k_gemm2(const unsigned short* __restrict__ H1b,
                                               const unsigned short* __restrict__ W2bb16,
                                               const unsigned short* __restrict__ W2ab16,
                                               const int* __restrict__ nodes,
                                               unsigned short* __restrict__ Yb16,
                                               float* __restrict__ Ya) {
    const int bb = blockIdx.x;
    const bool selfp = (bb >= 512);
    const unsigned short* B = selfp ? W2ab16 : W2bb16;
    const int blockM = (selfp ? (bb - 512) : bb) * 32;
    const int tid  = threadIdx.x;
    const int w    = tid >> 6;
    const int lane = tid & 63;
    const int l16  = lane & 15;
    const int quad = lane >> 4;
    int rsrc0 = blockM + l16,      rsrc1 = blockM + 16 + l16;
    if (selfp) { rsrc0 = nodes[rsrc0]; rsrc1 = nodes[rsrc1]; }
    short8 af[2][4], bfr[2][4];
#pragma unroll
    for (int c = 0; c < 4; ++c) {
        af[0][c] = *(const short8*)(H1b + (size_t)rsrc0 * 128 + c * 32 + quad * 8);
        af[1][c] = *(const short8*)(H1b + (size_t)rsrc1 * 128 + c * 32 + quad * 8);
    }
#pragma unroll
    for (int nt = 0; nt < 2; ++nt) {
        int n = w * 32 + nt * 16 + l16;
#pragma unroll
        for (int c = 0; c < 4; ++c)
            bfr[nt][c] = *(const short8*)(B + (size_t)n * 128 + c * 32 + quad * 8);
    }
    f32x4 acc[2][2] = {};
#pragma unroll
    for (int c = 0; c < 4; ++c)
#pragma unroll
        for (int mt = 0; mt < 2; ++mt)
#pragma unroll
            for (int nt = 0; nt < 2; ++nt)
                acc[mt][nt] = __builtin_amdgcn_mfma_f32_16x16x32_bf16(af[mt][c], bfr[nt][c], acc[mt][nt], 0, 0, 0);
#pragma unroll
    for (int mt = 0; mt < 2; ++mt)
#pragma unroll
        for (int nt = 0; nt < 2; ++nt) {
            int col = w * 32 + nt * 16 + l16;
#pragma unroll
            for (int r = 0; r < 4; ++r) {
                int row = blockM + mt * 16 + quad * 4 + r;
                if (selfp) Ya[(size_t)row * 128 + col] = acc[mt][nt][r];
                else       Yb16[(size_t)row * 128 + col] = f2bf(acc[mt][nt][r]);
            }
        }
}

// ---------------------------------------------------------------------------
// K4: layer-2 epilogue + classifier + softmax. ONE WAVE PER BATCH NODE.
// ---------------------------------------------------------------------------
__global__ __launch_bounds__(256) void k_l2head(const int* __restrict__ nodes,
                                                const unsigned short* __restrict__ nbr,
                                                const int* __restrict__ deg,
                                                const unsigned short* __restrict__ Yb16,
                                                const float* __restrict__ Ya,
                                                const float* __restrict__ b2,
                                                const float* __restrict__ Wl1t,
                                                const float* __restrict__ bl1,
                                                const float* __restrict__ Wl2,
                                                const float* __restrict__ bl2,
                                                float* __restrict__ out) {
    const int lane = threadIdx.x & 63;
    const int b = blockIdx.x * 4 + (threadIdx.x >> 6);
    const int n = nodes[b];
    const int cnt = deg[n];                      // full rowsum (divisor)
    const int gcnt = (cnt > MAXDEG) ? MAXDEG : cnt;  // CSR entries available
    const int myn  = (lane < gcnt)      ? (int)nbr[(size_t)n * MAXDEG + lane]      : 0;
    const int myn2 = (lane + 64 < gcnt) ? (int)nbr[(size_t)n * MAXDEG + lane + 64] : 0;
    const int half = lane >> 5, l32 = lane & 31;
    float ax = 0.f, ay = 0.f, az = 0.f, aw = 0.f;
    for (int k = half; k < gcnt; k += 2) {
        int kk = k & 63;
        int j1 = __shfl(myn, kk);
        int j2 = __shfl(myn2, kk);
        int j = (k < 64) ? j1 : j2;
        ushort4 y4 = *(const ushort4*)(Yb16 + (size_t)j * 128 + l32 * 4);
        ax += bf2f(y4.x); ay += bf2f(y4.y); az += bf2f(y4.z); aw += bf2f(y4.w);
    }
    ax += __shfl_xor(ax, 32); ay += __shfl_xor(ay, 32);
    az += __shfl_xor(az, 32); aw += __shfl_xor(aw, 32);
    float4 ya = *(const float4*)(Ya + (size_t)b * 128 + l32 * 4);
    float4 bb = *(const float4*)(b2 + l32 * 4);
    float fc = (float)cnt;
    float h0 = fmaxf(ya.x + ax / fc + bb.x, 0.f);
    float h1 = fmaxf(ya.y + ay / fc + bb.y, 0.f);
    float h2 = fmaxf(ya.z + az / fc + bb.z, 0.f);
    float h3 = fmaxf(ya.w + aw / fc + bb.w, 0.f);
    float s = h0 * h0 + h1 * h1 + h2 * h2 + h3 * h3;
#pragma unroll
    for (int off = 16; off > 0; off >>= 1) s += __shfl_xor(s, off);
    float rden = 1.0f / fmaxf(sqrtf(s), 1e-12f);
    h0 *= rden; h1 *= rden; h2 *= rden; h3 *= rden;
    // Lin: x[e] for e = 2*lane, 2*lane+1 (covers 128 cols across the wave)
    float2 bl = *(const float2*)(bl1 + 2 * lane);
    float x0 = bl.x, x1 = bl.y;
    const float* wl = Wl1t + 2 * lane;
    for (int m = 0; m < 32; ++m) {
        float k0 = __shfl(h0, m), k1 = __shfl(h1, m), k2 = __shfl(h2, m), k3 = __shfl(h3, m);
        float2 w0 = *(const float2*)(wl + (size_t)(m * 4 + 0) * 128);
        float2 w1 = *(const float2*)(wl + (size_t)(m * 4 + 1) * 128);
        float2 w2 = *(const float2*)(wl + (size_t)(m * 4 + 2) * 128);
        float2 w3 = *(const float2*)(wl + (size_t)(m * 4 + 3) * 128);
        x0 += k0 * w0.x + k1 * w1.x + k2 * w2.x + k3 * w3.x;
        x1 += k0 * w0.y + k1 * w1.y + k2 * w2.y + k3 * w3.y;
    }
    // head: 10 outputs, each a 64-lane tree reduce of 2-elem partials
    float cv[C_DIM];
#pragma unroll
    for (int cc = 0; cc < C_DIM; ++cc) {
        float2 w = *(const float2*)(Wl2 + (size_t)cc * 128 + 2 * lane);
        float p = x0 * w.x + x1 * w.y;
#pragma unroll
        for (int off = 32; off > 0; off >>= 1) p += __shfl_xor(p, off);
        cv[cc] = p + bl2[cc];
    }
    float mx = cv[0];
#pragma unroll
    for (int cc = 1; cc < C_DIM; ++cc) mx = fmaxf(mx, cv[cc]);
    float se = 0.f;
#pragma unroll
    for (int cc = 0; cc < C_DIM; ++cc) { cv[cc] = expf(cv[cc] - mx); se += cv[cc]; }
    float rse = 1.0f / se;
    float o = cv[0];
#pragma unroll
    for (int cc = 1; cc < C_DIM; ++cc) o = (lane == cc) ? cv[cc] : o;
    if (lane < C_DIM) out[(size_t)b * C_DIM + lane] = o * rse;
}

// ---------------------------------------------------------------------------
// Launch
// ---------------------------------------------------------------------------
extern "C" void kernel_launch(void* const* d_in, const int* in_sizes, int n_in,
                              void* d_out, int out_size, void* d_ws, size_t ws_size,
                              hipStream_t stream) {
    const int*   nodes = (const int*)  d_in[0];
    const float* adj   = (const float*)d_in[1];
    const float* data  = (const float*)d_in[2];
    const float* W1    = (const float*)d_in[3];
    const float* b1    = (const float*)d_in[4];
    const float* W2    = (const float*)d_in[5];
    const float* b2    = (const float*)d_in[6];
    const float* Wl1   = (const float*)d_in[7];
    const float* bl1   = (const float*)d_in[8];
    const float* Wl2   = (const float*)d_in[9];
    const float* bl2   = (const float*)d_in[10];
    float* out = (float*)d_out;

    // workspace: fp32 first, then bf16/ushort, then int (16B aligned)
    float* Wl1t = (float*)d_ws;                              // 128*128
    float* Ya   = Wl1t + 16384;                              // 4096*128
    unsigned short* W2ab16 = (unsigned short*)(Ya + (size_t)B_DIM * 128); // 128*128
    unsigned short* W2bb16 = W2ab16 + 16384;                 // 128*128
    unsigned short* Xb16   = W2bb16 + 16384;                 // 16384*256
    unsigned short* H1b    = Xb16 + (size_t)N_NODES * 256;   // 16384*128
    unsigned short* Yb16   = H1b + (size_t)N_NODES * 128;    // 16384*128
    unsigned short* nbr    = Yb16 + (size_t)N_NODES * 128;   // 16384*128
    int* deg = (int*)(nbr + (size_t)N_NODES * MAXDEG);       // 16384

    // K1: weight prep + GEMM1 (Xb16 must be ready before K2)
    k_prep1<<<656, 256, 0, stream>>>(data, W1, W2, Wl1,
                                     Xb16, W2ab16, W2bb16, Wl1t);
    // K2: FUSED adj scan + layer-1 aggregation + relu + l2norm (wave-per-row)
    k_scanagg<<<N_NODES / 4, 256, 0, stream>>>(adj, Xb16, b1, nbr, deg, H1b);
    // K3: barrier-less GEMM2 (Yb all nodes + Ya batch rows)
    k_gemm2<<<512 + 128, 256, 0, stream>>>(H1b, W2bb16, W2ab16, nodes, Yb16, Ya);
    // K4: wave-per-batch-node layer-2 + head
    k_l2head<<<B_DIM / 4, 256, 0, stream>>>(nodes, nbr, deg, Yb16, Ya, b2,
                                            Wl1t, bl1, Wl2, bl2, out);
}